// Round 3
// baseline (297.543 us; speedup 1.0000x reference)
//
#include <hip/hip_runtime.h>
#include <hip/hip_bf16.h>
#include <math.h>

#define B_ 2
#define T_ 2048
#define D_ 2048
#define H_ 16
#define KV_ 4
#define HD_ 128
#define REP_ 4
#define QKVSTR 3072

typedef __attribute__((ext_vector_type(8))) short s16x8;
typedef __attribute__((ext_vector_type(4))) short s16x4;
typedef __attribute__((ext_vector_type(4))) float f32x4;
typedef __attribute__((ext_vector_type(16))) float f32x16;
typedef __hip_bfloat16 bf16;

__device__ __forceinline__ short f2bf(float x) {
    bf16 h = __float2bfloat16(x);
    return *reinterpret_cast<short*>(&h);
}

__device__ __forceinline__ void gl2lds16(const void* g, void* l) {
    __builtin_amdgcn_global_load_lds(
        (const __attribute__((address_space(1))) char*)g,
        (__attribute__((address_space(3))) char*)l, 16, 0, 0);
}

// ---------------- fused prep: cast x -> bf16  +  all 4 weight transposes ----
__global__ __launch_bounds__(256) void prep(const float* __restrict__ x,
                                            const float* __restrict__ Wq,
                                            const float* __restrict__ Wk,
                                            const float* __restrict__ Wv,
                                            const float* __restrict__ Wo,
                                            bf16* __restrict__ xb,
                                            bf16* __restrict__ Wqkvt,
                                            bf16* __restrict__ Wot,
                                            float qscale) {
    const int bid = blockIdx.x;
    const int t = threadIdx.x;
    if (bid < 4096) {
        int i = (bid * 256 + t) * 8;
        float4 a = *(const float4*)(x + i);
        float4 b = *(const float4*)(x + i + 4);
        short o[8] = {f2bf(a.x), f2bf(a.y), f2bf(a.z), f2bf(a.w),
                      f2bf(b.x), f2bf(b.y), f2bf(b.z), f2bf(b.w)};
        *(s16x8*)(xb + i) = *(const s16x8*)o;
        return;
    }
    __shared__ short tile[64 * 72];
    const float* W; bf16* dst; int N; float scale; int seg;
    if (bid < 5120)      { seg = bid - 4096; W = Wq; dst = Wqkvt;                      N = 2048; scale = qscale; }
    else if (bid < 5376) { seg = bid - 5120; W = Wk; dst = Wqkvt + (size_t)2048 * D_;  N = 512;  scale = 1.f; }
    else if (bid < 5632) { seg = bid - 5376; W = Wv; dst = Wqkvt + (size_t)2560 * D_;  N = 512;  scale = 1.f; }
    else                 { seg = bid - 5632; W = Wo; dst = Wot;                        N = 2048; scale = 1.f; }
    const int k0 = (seg & 31) * 64, n0 = (seg >> 5) * 64;
    const int r = t >> 2, c0 = (t & 3) * 16;
    const float* src = W + (size_t)(k0 + r) * N + n0 + c0;
    #pragma unroll
    for (int i = 0; i < 16; i += 4) {
        float4 v = *(const float4*)(src + i);
        tile[r * 72 + c0 + i + 0] = f2bf(v.x * scale);
        tile[r * 72 + c0 + i + 1] = f2bf(v.y * scale);
        tile[r * 72 + c0 + i + 2] = f2bf(v.z * scale);
        tile[r * 72 + c0 + i + 3] = f2bf(v.w * scale);
    }
    __syncthreads();
    short tmp[16];
    #pragma unroll
    for (int i = 0; i < 16; ++i) tmp[i] = tile[(c0 + i) * 72 + r];
    bf16* d = dst + (size_t)(n0 + r) * D_ + k0 + c0;
    *(s16x8*)(d)     = *(const s16x8*)&tmp[0];
    *(s16x8*)(d + 8) = *(const s16x8*)&tmp[8];
}

// ---------------- bf16 NT GEMM: C[M,N] = A[M,K] * Bt[N,K]^T ----------------
// (256,3): cap the allocator at ~170 VGPR so 3 blocks/CU stay resident —
// with a bare (256) bound the allocator can exceed 170 and the K-loop runs
// at 2 blocks/CU, latency-starved (~480 TF observed). State fits: acc 64 +
// frags 32 + addressing ~50. WVT: V block of QKV also stored transposed.
template<typename OUTT, int ROUND, int WVT>
__global__ __launch_bounds__(256, 3) void gemm_nt(const bf16* __restrict__ A,
                                                  const bf16* __restrict__ Bt,
                                                  OUTT* __restrict__ C,
                                                  bf16* __restrict__ Vtg,
                                                  int M, int N, int K) {
    __shared__ short As[128 * 64];
    __shared__ short Bs[128 * 64];
    const int tid = threadIdx.x;
    const int lane = tid & 63;
    const int wave = tid >> 6;
    const int quad = lane >> 4;
    const int l16 = lane & 15;
    const int wr = wave >> 1, wc = wave & 1;
    const int row0 = blockIdx.y * 128;
    const int col0 = blockIdx.x * 128;

    f32x4 acc[4][4] = {};

    for (int k0 = 0; k0 < K; k0 += 64) {
        __syncthreads();
        #pragma unroll
        for (int i = 0; i < 4; ++i) {
            int g = i * 256 + tid;
            int row = g >> 3;
            int cs = (g & 7) ^ (row & 7);
            gl2lds16(A + (size_t)(row0 + row) * K + k0 + cs * 8, &As[g * 8]);
        }
        #pragma unroll
        for (int i = 0; i < 4; ++i) {
            int g = i * 256 + tid;
            int row = g >> 3;
            int cs = (g & 7) ^ (row & 7);
            gl2lds16(Bt + (size_t)(col0 + row) * K + k0 + cs * 8, &Bs[g * 8]);
        }
        __syncthreads();
        #pragma unroll
        for (int kk = 0; kk < 2; ++kk) {
            s16x8 af[4], bfr[4];
            #pragma unroll
            for (int i = 0; i < 4; ++i) {
                int row = wr * 64 + i * 16 + l16;
                int c = (kk * 4 + quad) ^ (row & 7);
                af[i] = *(const s16x8*)&As[row * 64 + c * 8];
            }
            #pragma unroll
            for (int j = 0; j < 4; ++j) {
                int row = wc * 64 + j * 16 + l16;
                int c = (kk * 4 + quad) ^ (row & 7);
                bfr[j] = *(const s16x8*)&Bs[row * 64 + c * 8];
            }
            #pragma unroll
            for (int i = 0; i < 4; ++i)
                #pragma unroll
                for (int j = 0; j < 4; ++j)
                    acc[i][j] = __builtin_amdgcn_mfma_f32_16x16x32_bf16(
                        af[i], bfr[j], acc[i][j], 0, 0, 0);
        }
    }

    #pragma unroll
    for (int i = 0; i < 4; ++i) {
        #pragma unroll
        for (int j = 0; j < 4; ++j) {
            const int col = col0 + wc * 64 + j * 16 + l16;
            const int rowb = row0 + wr * 64 + i * 16 + quad * 4;
            #pragma unroll
            for (int r = 0; r < 4; ++r) {
                float v = acc[i][j][r];
                if (ROUND) v = rintf(v * 1e4f) * 1e-4f;
                if constexpr (sizeof(OUTT) == 2)
                    C[(size_t)(rowb + r) * N + col] = __float2bfloat16(v);
                else
                    C[(size_t)(rowb + r) * N + col] = v;
            }
            if constexpr (WVT) {
                if (col >= 2560) {
                    const int dcol = (col - 2560) & 127;
                    const int g = (col - 2560) >> 7;
                    const int b = rowb >> 11;
                    const int t = rowb & 2047;
                    short pk[4] = {f2bf(acc[i][j][0]), f2bf(acc[i][j][1]),
                                   f2bf(acc[i][j][2]), f2bf(acc[i][j][3])};
                    *(s16x4*)&Vtg[(size_t)((b * KV_ + g) * HD_ + dcol) * T_ + t] =
                        *(const s16x4*)pk;
                }
            }
        }
    }
}

// ---------------- MFMA flash attention v10: 32x32x16, P in registers, ------
// ---------------- 3 blocks/CU ----------------------------------------------
// flash9 post-mortem: inner loop is right (in-register P via swapped QK^T +
// cvt_pk/permlane32_swap, 32 ds_read_b128 per 1.05 MFLOP), but 64 KiB
// double-buffer capped residency at 2 blocks/CU (Occupancy 12.4%, MfmaUtil
// 18%) — latency-starved, worse than flash7's 3-block 68 us. The LDS-pipe
// floor for this structure is ~29 us/CU; the rest was stall.
// v10: single 32 KiB buffer -> 3 blocks/CU (96 KiB LDS); stage latency is
// hidden by cross-block overlap (m114 mechanism, proven at 3 blocks/CU in
// flash7/m97). To fit (256,3)'s ~170-VGPR unified cap WITHOUT flash8's
// spill, the two 32-s halves (mt) are processed sequentially: only one
// f32x16 sacc live (peak ~150: oacc 64 + qf 32 + sacc 16 + temps).
// Bonus: the fully-masked upper half of diagonal tiles is skipped instead
// of computed as exp(-inf), and masking is per-half. s_setprio(1) wraps
// the MFMA clusters (T5; 12 waves/CU gives the scheduler real arbitration).
__global__ __launch_bounds__(256, 3) void flash10(const bf16* __restrict__ Q,
                                                  const bf16* __restrict__ K,
                                                  const bf16* __restrict__ Vtg,
                                                  bf16* __restrict__ O) {
    __shared__ short smem[16384];   // 32 KiB: Kt [64s][128d] swz16 | Vt [128d][64s] swz8

    const int h = blockIdx.x;
    const int b = blockIdx.y & 1;
    const int qt = 15 - (blockIdx.y >> 1);   // heavy blocks first (LPT)
    const int g = h >> 2;
    const int tid = threadIdx.x;
    const int lane = tid & 63;
    const int wave = tid >> 6;
    const int l32 = lane & 31;
    const int hi = lane >> 5;                // which k-half of the frag
    const int qw0 = qt * 128 + wave * 32;    // this wave's first q row
    const int qg = qw0 + l32;                // this lane's q row

    // Q fragments (B-operand): n=l32 (q), k = hi*8 + j (d); 8 k-tiles of 16
    s16x8 qf[8];
    {
        const bf16* qp = Q + (size_t)(b * T_ + qg) * QKVSTR + h * HD_ + hi * 8;
        #pragma unroll
        for (int kt = 0; kt < 8; ++kt) qf[kt] = *(const s16x8*)(qp + kt * 16);
    }

    const bf16* Kp = K + (size_t)(b * T_) * QKVSTR + g * HD_;
    const bf16* Vp = Vtg + (size_t)((b * KV_ + g) * HD_) * T_;

    float l_part = 0.f;
    f32x16 oacc[4] = {};

    const int jmax = 2 * qt + 1;
    for (int j = 0; j <= jmax; ++j) {
        const int s0 = j * 64;
        __syncthreads();                     // all waves done reading tile j-1
        // stage K tile: 64 s-rows x 128 d, 16-chunk XOR swizzle (^ s&15)
        #pragma unroll
        for (int i = 0; i < 4; ++i) {
            int g2 = i * 256 + tid;
            int s = g2 >> 4;
            int cs = (g2 & 15) ^ (s & 15);
            gl2lds16(Kp + (size_t)(s0 + s) * QKVSTR + cs * 8, &smem[g2 * 8]);
        }
        // stage V tile: 128 d-rows x 64 s, 8-chunk XOR swizzle (^ d&7)
        #pragma unroll
        for (int i = 0; i < 4; ++i) {
            int g2 = i * 256 + tid;
            int d = g2 >> 3;
            int cs = (g2 & 7) ^ (d & 7);
            gl2lds16(Vp + (size_t)d * T_ + s0 + cs * 8, &smem[8192 + g2 * 8]);
        }
        __syncthreads();                     // vmcnt(0) drain + tile j visible

        if (s0 >= qw0 + 32) continue;        // tile fully masked for this wave

        #pragma unroll
        for (int mt = 0; mt < 2; ++mt) {
            if (s0 + mt * 32 > qw0 + 31) continue;  // upper half fully masked
            // S = K·Q^T : n=q=l32, m=s in [s0+mt*32, s0+mt*32+32)
            f32x16 sacc = {};
            __builtin_amdgcn_s_setprio(1);
            #pragma unroll
            for (int kt = 0; kt < 8; ++kt) {
                int s = mt * 32 + l32;
                int c = (kt * 2 + hi) ^ (s & 15);
                const s16x8 kf = *(const s16x8*)&smem[s * 128 + c * 8];
                sacc = __builtin_amdgcn_mfma_f32_32x32x16_bf16(
                    kf, qf[kt], sacc, 0, 0, 0);
            }
            __builtin_amdgcn_s_setprio(0);

            // static softmax: P = exp2(s) (scale folded into Wq); masked -> 0
            const bool diagm = (s0 + mt * 32 + 31 > qw0);
            #pragma unroll
            for (int r = 0; r < 16; ++r) {
                float sv = sacc[r];
                if (diagm) {
                    int sg = s0 + mt * 32 + (r & 3) + 8 * (r >> 2) + 4 * hi;
                    if (sg > qg) sv = -INFINITY;
                }
                float e = exp2f(sv);
                sacc[r] = e;
                l_part += e;
            }

            // P -> bf16 A-frags in registers: regs o..o+7 cover the 16-s
            // k-tile; cvt_pk pairs + permlane32_swap fix the lane-half
            // split: swap(w01,w45) -> {A0,A2}, swap(w23,w67) -> {A1,A3}.
            #pragma unroll
            for (int kts = 0; kts < 2; ++kts) {
                const int o = kts * 8;
                unsigned w01, w23, w45, w67;
                asm("v_cvt_pk_bf16_f32 %0, %1, %2"
                    : "=v"(w01) : "v"(sacc[o + 0]), "v"(sacc[o + 1]));
                asm("v_cvt_pk_bf16_f32 %0, %1, %2"
                    : "=v"(w23) : "v"(sacc[o + 2]), "v"(sacc[o + 3]));
                asm("v_cvt_pk_bf16_f32 %0, %1, %2"
                    : "=v"(w45) : "v"(sacc[o + 4]), "v"(sacc[o + 5]));
                asm("v_cvt_pk_bf16_f32 %0, %1, %2"
                    : "=v"(w67) : "v"(sacc[o + 6]), "v"(sacc[o + 7]));
                asm("v_permlane32_swap_b32 %0, %1" : "+v"(w01), "+v"(w45));
                asm("v_permlane32_swap_b32 %0, %1" : "+v"(w23), "+v"(w67));
                union { unsigned u[4]; s16x8 v; } pu;
                pu.u[0] = w01; pu.u[1] = w23; pu.u[2] = w45; pu.u[3] = w67;
                const s16x8 pa = pu.v;
                // O += P·V : A=pa (m=q=l32, k=s), B=V (k=s, n=d=l32)
                __builtin_amdgcn_s_setprio(1);
                #pragma unroll
                for (int nt = 0; nt < 4; ++nt) {
                    int d = nt * 32 + l32;
                    int c = ((mt * 2 + kts) * 2 + hi) ^ (d & 7);
                    const s16x8 vf = *(const s16x8*)&smem[8192 + d * 64 + c * 8];
                    oacc[nt] = __builtin_amdgcn_mfma_f32_32x32x16_bf16(
                        pa, vf, oacc[nt], 0, 0, 0);
                }
                __builtin_amdgcn_s_setprio(0);
            }
        }
    }

    // full row sum: the other 32 s of each tile live in the lane^32 partner
    l_part += __shfl_xor(l_part, 32);
    const float invl = 1.f / l_part;     // valid for q = qw0 + l32

    // epilogue: oacc rows are q=(r&3)+8*(r>>2)+4*hi, cols d=nt*32+l32
    bf16* op = O + (size_t)(b * T_ + qw0) * (H_ * HD_) + h * HD_;
    #pragma unroll
    for (int r = 0; r < 16; ++r) {
        const int qrow = (r & 3) + 8 * (r >> 2) + 4 * hi;
        const float il = __shfl(invl, qrow);
        #pragma unroll
        for (int nt = 0; nt < 4; ++nt)
            op[(size_t)qrow * (H_ * HD_) + nt * 32 + l32] =
                __float2bfloat16(oacc[nt][r] * il);
    }
}

extern "C" void kernel_launch(void* const* d_in, const int* in_sizes, int n_in,
                              void* d_out, int out_size, void* d_ws, size_t ws_size,
                              hipStream_t stream) {
    const float* x  = (const float*)d_in[0];
    const float* Wq = (const float*)d_in[1];
    const float* Wk = (const float*)d_in[2];
    const float* Wv = (const float*)d_in[3];
    const float* Wo = (const float*)d_in[4];
    float* out = (float*)d_out;

    const size_t NR = (size_t)B_ * T_;               // 4096
    bf16* ws = (bf16*)d_ws;
    bf16* xb    = ws;                                 // 4096*2048
    bf16* Wqkvt = xb + NR * D_;                       // 3072*2048
    bf16* Wot   = Wqkvt + (size_t)QKVSTR * D_;        // 2048*2048
    bf16* QKVb  = Wot + (size_t)D_ * D_;              // 4096*3072
    bf16* Vtg   = QKVb + NR * QKVSTR;                 // 2*4*128*2048
    bf16* Ab    = Vtg + (size_t)B_ * KV_ * HD_ * T_;  // 4096*2048

    const float qscale = 1.4426950408889634f / sqrtf((float)HD_);

    prep<<<6656, 256, 0, stream>>>(x, Wq, Wk, Wv, Wo, xb, Wqkvt, Wot, qscale);

    // fused QKV projection; V columns also written transposed into Vtg
    gemm_nt<bf16, 0, 1><<<dim3(QKVSTR / 128, NR / 128), 256, 0, stream>>>(
        xb, Wqkvt, QKVb, Vtg, (int)NR, QKVSTR, D_);

    flash10<<<dim3(H_, 32), 256, 0, stream>>>(QKVb, QKVb + 2048, Vtg, Ab);

    gemm_nt<float, 1, 0><<<dim3(D_ / 128, NR / 128), 256, 0, stream>>>(
        Ab, Wot, out, nullptr, (int)NR, D_, H_ * HD_);
}

// Round 4
// 287.394 us; speedup vs baseline: 1.0353x; 1.0353x over previous
//
#include <hip/hip_runtime.h>
#include <hip/hip_bf16.h>
#include <math.h>

#define B_ 2
#define T_ 2048
#define D_ 2048
#define H_ 16
#define KV_ 4
#define HD_ 128
#define REP_ 4
#define QKVSTR 3072

typedef __attribute__((ext_vector_type(8))) short s16x8;
typedef __attribute__((ext_vector_type(4))) short s16x4;
typedef __attribute__((ext_vector_type(4))) float f32x4;
typedef __attribute__((ext_vector_type(16))) float f32x16;
typedef __hip_bfloat16 bf16;

__device__ __forceinline__ short f2bf(float x) {
    bf16 h = __float2bfloat16(x);
    return *reinterpret_cast<short*>(&h);
}

__device__ __forceinline__ void gl2lds16(const void* g, void* l) {
    __builtin_amdgcn_global_load_lds(
        (const __attribute__((address_space(1))) char*)g,
        (__attribute__((address_space(3))) char*)l, 16, 0, 0);
}

// ---------------- fused prep: cast x -> bf16  +  all 4 weight transposes ----
__global__ __launch_bounds__(256) void prep(const float* __restrict__ x,
                                            const float* __restrict__ Wq,
                                            const float* __restrict__ Wk,
                                            const float* __restrict__ Wv,
                                            const float* __restrict__ Wo,
                                            bf16* __restrict__ xb,
                                            bf16* __restrict__ Wqkvt,
                                            bf16* __restrict__ Wot,
                                            float qscale) {
    const int bid = blockIdx.x;
    const int t = threadIdx.x;
    if (bid < 4096) {
        int i = (bid * 256 + t) * 8;
        float4 a = *(const float4*)(x + i);
        float4 b = *(const float4*)(x + i + 4);
        short o[8] = {f2bf(a.x), f2bf(a.y), f2bf(a.z), f2bf(a.w),
                      f2bf(b.x), f2bf(b.y), f2bf(b.z), f2bf(b.w)};
        *(s16x8*)(xb + i) = *(const s16x8*)o;
        return;
    }
    __shared__ short tile[64 * 72];
    const float* W; bf16* dst; int N; float scale; int seg;
    if (bid < 5120)      { seg = bid - 4096; W = Wq; dst = Wqkvt;                      N = 2048; scale = qscale; }
    else if (bid < 5376) { seg = bid - 5120; W = Wk; dst = Wqkvt + (size_t)2048 * D_;  N = 512;  scale = 1.f; }
    else if (bid < 5632) { seg = bid - 5376; W = Wv; dst = Wqkvt + (size_t)2560 * D_;  N = 512;  scale = 1.f; }
    else                 { seg = bid - 5632; W = Wo; dst = Wot;                        N = 2048; scale = 1.f; }
    const int k0 = (seg & 31) * 64, n0 = (seg >> 5) * 64;
    const int r = t >> 2, c0 = (t & 3) * 16;
    const float* src = W + (size_t)(k0 + r) * N + n0 + c0;
    #pragma unroll
    for (int i = 0; i < 16; i += 4) {
        float4 v = *(const float4*)(src + i);
        tile[r * 72 + c0 + i + 0] = f2bf(v.x * scale);
        tile[r * 72 + c0 + i + 1] = f2bf(v.y * scale);
        tile[r * 72 + c0 + i + 2] = f2bf(v.z * scale);
        tile[r * 72 + c0 + i + 3] = f2bf(v.w * scale);
    }
    __syncthreads();
    short tmp[16];
    #pragma unroll
    for (int i = 0; i < 16; ++i) tmp[i] = tile[(c0 + i) * 72 + r];
    bf16* d = dst + (size_t)(n0 + r) * D_ + k0 + c0;
    *(s16x8*)(d)     = *(const s16x8*)&tmp[0];
    *(s16x8*)(d + 8) = *(const s16x8*)&tmp[8];
}

// ---- bf16 NT GEMM, 8-wave BMx256 tile, counted-vmcnt pipeline (T4) --------
// Old 128^2/2-barrier gemm_nt ran at ~490 TF (K=2048 shape, m102-consistent).
// This version: BM = MI*32 rows x 256 cols per block, 8 waves (512 thr,
// wave grid 2Mx4N, per-wave MI*16 x 64 out), BK=64, double-buffered LDS.
// Pipeline per K-step t (the m218 lever: vmcnt NEVER drains to 0 mid-loop):
//   issue next tile's 8 global_load_lds  -> buf[(t+1)&1]
//   s_waitcnt vmcnt(8)  (waits only L(t); L(t+1) stays in flight)
//   s_barrier           (A: everyone's L(t) landed; prior readers of
//                        buf[(t+1)&1] finished at iter t-1's barrier B)
//   24 ds_read_b128 + 64 MFMA per wave from buf[t&1] (compiler lgkmcnt)
//   s_waitcnt lgkmcnt(0); s_barrier   (B: my reads of buf[t&1] are complete
//                        before any wave's L(t+2) can overwrite it)
// Raw s_barrier (not __syncthreads) avoids the compiler's vmcnt(0) drain.
// gemm1: MI=8 -> 256x256, 192 blocks, 128 KiB LDS, 1 block/CU.
// gemm2: MI=4 -> 128x256, 256 blocks,  96 KiB LDS, 1 block/CU.
template<int MI, int LA, typename OUTT, int ROUND, int WVT>
__global__ __launch_bounds__(512, 2) void gemm8(const bf16* __restrict__ A,
                                                const bf16* __restrict__ Bt,
                                                OUTT* __restrict__ C,
                                                bf16* __restrict__ Vtg,
                                                int M, int N, int K) {
    constexpr int ASZ = MI * 2048;          // shorts per A buffer (MI*32 x 64)
    constexpr int BSZ = 16384;              // shorts per B buffer (256 x 64)
    __shared__ short smem[2 * (ASZ + BSZ)];
    const int tid = threadIdx.x;
    const int lane = tid & 63;
    const int wave = tid >> 6;
    const int quad = lane >> 4;
    const int l16 = lane & 15;
    const int wr = wave >> 2, wc = wave & 3;      // 2 x 4 wave grid
    const int row0 = blockIdx.y * (MI * 32);
    const int col0 = blockIdx.x * 256;
    const int NT = K >> 6;

    f32x4 acc[MI][4] = {};

    const bf16* Ap = A + (size_t)row0 * K;
    const bf16* Bp = Bt + (size_t)col0 * K;

    auto stage = [&](int t) {
        const int bo = (t & 1) * (ASZ + BSZ);
        const int k0 = t * 64;
        #pragma unroll
        for (int i = 0; i < LA; ++i) {
            int g = i * 512 + tid;
            int row = g >> 3;
            int cs = (g & 7) ^ (row & 7);
            gl2lds16(Ap + (size_t)row * K + k0 + cs * 8, &smem[bo + g * 8]);
        }
        #pragma unroll
        for (int i = 0; i < 4; ++i) {
            int g = i * 512 + tid;
            int row = g >> 3;
            int cs = (g & 7) ^ (row & 7);
            gl2lds16(Bp + (size_t)row * K + k0 + cs * 8, &smem[bo + ASZ + g * 8]);
        }
    };

    stage(0);
    for (int t = 0; t < NT; ++t) {
        if (t + 1 < NT) {
            stage(t + 1);
            // wait L(t) only; the 8 loads of L(t+1) stay in flight
            if constexpr (LA == 4) asm volatile("s_waitcnt vmcnt(8)" ::: "memory");
            else                   asm volatile("s_waitcnt vmcnt(6)" ::: "memory");
        } else {
            asm volatile("s_waitcnt vmcnt(0)" ::: "memory");
        }
        __builtin_amdgcn_s_barrier();
        asm volatile("" ::: "memory");            // no LDS reads hoist above A

        const int bo = (t & 1) * (ASZ + BSZ);
        #pragma unroll
        for (int kk = 0; kk < 2; ++kk) {
            s16x8 af[MI], bfr[4];
            #pragma unroll
            for (int i = 0; i < MI; ++i) {
                int row = wr * (MI * 16) + i * 16 + l16;
                int c = (kk * 4 + quad) ^ (row & 7);
                af[i] = *(const s16x8*)&smem[bo + row * 64 + c * 8];
            }
            #pragma unroll
            for (int j = 0; j < 4; ++j) {
                int row = wc * 64 + j * 16 + l16;
                int c = (kk * 4 + quad) ^ (row & 7);
                bfr[j] = *(const s16x8*)&smem[bo + ASZ + row * 64 + c * 8];
            }
            __builtin_amdgcn_s_setprio(1);
            #pragma unroll
            for (int i = 0; i < MI; ++i)
                #pragma unroll
                for (int j = 0; j < 4; ++j)
                    acc[i][j] = __builtin_amdgcn_mfma_f32_16x16x32_bf16(
                        af[i], bfr[j], acc[i][j], 0, 0, 0);
            __builtin_amdgcn_s_setprio(0);
        }
        // my ds_reads of buf[t&1] complete before crossing B
        asm volatile("s_waitcnt lgkmcnt(0)" ::: "memory");
        __builtin_amdgcn_s_barrier();
        asm volatile("" ::: "memory");
    }

    #pragma unroll
    for (int i = 0; i < MI; ++i) {
        #pragma unroll
        for (int j = 0; j < 4; ++j) {
            const int col = col0 + wc * 64 + j * 16 + l16;
            const int rowb = row0 + wr * (MI * 16) + i * 16 + quad * 4;
            #pragma unroll
            for (int r = 0; r < 4; ++r) {
                float v = acc[i][j][r];
                if (ROUND) v = rintf(v * 1e4f) * 1e-4f;
                if constexpr (sizeof(OUTT) == 2)
                    C[(size_t)(rowb + r) * N + col] = __float2bfloat16(v);
                else
                    C[(size_t)(rowb + r) * N + col] = v;
            }
            if constexpr (WVT) {
                if (col >= 2560) {
                    const int dcol = (col - 2560) & 127;
                    const int g = (col - 2560) >> 7;
                    const int b = rowb >> 11;
                    const int t = rowb & 2047;
                    short pk[4] = {f2bf(acc[i][j][0]), f2bf(acc[i][j][1]),
                                   f2bf(acc[i][j][2]), f2bf(acc[i][j][3])};
                    *(s16x4*)&Vtg[(size_t)((b * KV_ + g) * HD_ + dcol) * T_ + t] =
                        *(const s16x4*)pk;
                }
            }
        }
    }
}

// ---------------- MFMA flash attention v9 (best measured: 75 us) -----------
// 32x32x16, swapped QK^T, P in registers via cvt_pk+permlane32_swap, LDS
// double-buffer 2x32 KiB, one __syncthreads per iter (its vmcnt(0) drain IS
// the intended depth-1 pipeline semantics). Grid is 512 blocks = 2/CU hard
// cap (32 q/wave fixes total waves at 8/CU); flash10 proved removing the
// intra-block dbuf at this residency costs +28 us. Kept verbatim.
__global__ __launch_bounds__(256, 2) void flash9(const bf16* __restrict__ Q,
                                                 const bf16* __restrict__ K,
                                                 const bf16* __restrict__ Vtg,
                                                 bf16* __restrict__ O) {
    __shared__ short smem[32768];   // 2 buffers x (Kt [64s][128d] + Vt [128d][64s])

    const int h = blockIdx.x;
    const int b = blockIdx.y & 1;
    const int qt = 15 - (blockIdx.y >> 1);   // heavy blocks first (LPT)
    const int g = h >> 2;
    const int tid = threadIdx.x;
    const int lane = tid & 63;
    const int wave = tid >> 6;
    const int l32 = lane & 31;
    const int hi = lane >> 5;                // which k-half of the frag
    const int qw0 = qt * 128 + wave * 32;    // this wave's first q row
    const int qg = qw0 + l32;                // this lane's q row

    // Q fragments (B-operand): n=l32 (q), k = hi*8 + j (d); 8 k-tiles of 16
    s16x8 qf[8];
    {
        const bf16* qp = Q + (size_t)(b * T_ + qg) * QKVSTR + h * HD_ + hi * 8;
        #pragma unroll
        for (int kt = 0; kt < 8; ++kt) qf[kt] = *(const s16x8*)(qp + kt * 16);
    }

    const bf16* Kp = K + (size_t)(b * T_) * QKVSTR + g * HD_;
    const bf16* Vp = Vtg + (size_t)((b * KV_ + g) * HD_) * T_;

    float l_part = 0.f;
    f32x16 oacc[4] = {};

    const int jmax = 2 * qt + 1;

    // prologue: stage tile 0 into buffer 0
    #pragma unroll
    for (int i = 0; i < 4; ++i) {
        int g2 = i * 256 + tid;
        int s = g2 >> 4;
        int cs = (g2 & 15) ^ (s & 15);
        gl2lds16(Kp + (size_t)s * QKVSTR + cs * 8, &smem[g2 * 8]);
    }
    #pragma unroll
    for (int i = 0; i < 4; ++i) {
        int g2 = i * 256 + tid;
        int d = g2 >> 3;
        int cs = (g2 & 7) ^ (d & 7);
        gl2lds16(Vp + (size_t)d * T_ + cs * 8, &smem[8192 + g2 * 8]);
    }

    for (int j = 0; j <= jmax; ++j) {
        const int kb = (j & 1) << 14;        // 16384 shorts per buffer
        // drains tile j's loads (vmcnt(0) before s_barrier) AND ensures all
        // waves finished reading the buffer tile j+1 is about to overwrite
        __syncthreads();

        if (j < jmax) {                      // stage tile j+1 (block-uniform)
            const int s0n = (j + 1) * 64;
            const int nb = ((j + 1) & 1) << 14;
            #pragma unroll
            for (int i = 0; i < 4; ++i) {
                int g2 = i * 256 + tid;
                int s = g2 >> 4;
                int cs = (g2 & 15) ^ (s & 15);
                gl2lds16(Kp + (size_t)(s0n + s) * QKVSTR + cs * 8, &smem[nb + g2 * 8]);
            }
            #pragma unroll
            for (int i = 0; i < 4; ++i) {
                int g2 = i * 256 + tid;
                int d = g2 >> 3;
                int cs = (g2 & 7) ^ (d & 7);
                gl2lds16(Vp + (size_t)d * T_ + s0n + cs * 8, &smem[nb + 8192 + g2 * 8]);
            }
        }

        const int s0 = j * 64;
        if (s0 >= qw0 + 32) continue;        // tile fully masked for this wave

        // S = K·Q^T : sacc[mt] has n=q=l32, m=s (two 32-s halves)
        f32x16 sacc[2] = {};
        #pragma unroll
        for (int kt = 0; kt < 8; ++kt) {
            #pragma unroll
            for (int mt = 0; mt < 2; ++mt) {
                int s = mt * 32 + l32;
                int c = (kt * 2 + hi) ^ (s & 15);
                const s16x8 kf = *(const s16x8*)&smem[kb + s * 128 + c * 8];
                sacc[mt] = __builtin_amdgcn_mfma_f32_32x32x16_bf16(
                    kf, qf[kt], sacc[mt], 0, 0, 0);
            }
        }

        const bool diagw = (s0 + 63 > qw0);
        #pragma unroll
        for (int mt = 0; mt < 2; ++mt) {
            // static softmax: P = exp2(s) (scale folded into Wq); masked -> 0
            #pragma unroll
            for (int r = 0; r < 16; ++r) {
                float sv = sacc[mt][r];
                if (diagw) {
                    int sg = s0 + mt * 32 + (r & 3) + 8 * (r >> 2) + 4 * hi;
                    if (sg > qg) sv = -INFINITY;
                }
                float e = exp2f(sv);
                sacc[mt][r] = e;
                l_part += e;
            }
            // P -> bf16 A-frags in registers: regs o..o+7 cover the 16-s
            // k-tile kts; cvt_pk pairs + permlane32_swap fix the lane-half
            // split: swap(w01,w45) -> {A0,A2}, swap(w23,w67) -> {A1,A3}.
            #pragma unroll
            for (int kts = 0; kts < 2; ++kts) {
                const int o = kts * 8;
                unsigned w01, w23, w45, w67;
                asm("v_cvt_pk_bf16_f32 %0, %1, %2"
                    : "=v"(w01) : "v"(sacc[mt][o + 0]), "v"(sacc[mt][o + 1]));
                asm("v_cvt_pk_bf16_f32 %0, %1, %2"
                    : "=v"(w23) : "v"(sacc[mt][o + 2]), "v"(sacc[mt][o + 3]));
                asm("v_cvt_pk_bf16_f32 %0, %1, %2"
                    : "=v"(w45) : "v"(sacc[mt][o + 4]), "v"(sacc[mt][o + 5]));
                asm("v_cvt_pk_bf16_f32 %0, %1, %2"
                    : "=v"(w67) : "v"(sacc[mt][o + 6]), "v"(sacc[mt][o + 7]));
                asm("v_permlane32_swap_b32 %0, %1" : "+v"(w01), "+v"(w45));
                asm("v_permlane32_swap_b32 %0, %1" : "+v"(w23), "+v"(w67));
                union { unsigned u[4]; s16x8 v; } pu;
                pu.u[0] = w01; pu.u[1] = w23; pu.u[2] = w45; pu.u[3] = w67;
                const s16x8 pa = pu.v;
                // O += P·V : A=pa (m=q=l32, k=s), B=V (k=s, n=d=l32)
                #pragma unroll
                for (int nt = 0; nt < 4; ++nt) {
                    int d = nt * 32 + l32;
                    int c = ((mt * 2 + kts) * 2 + hi) ^ (d & 7);
                    const s16x8 vf = *(const s16x8*)&smem[kb + 8192 + d * 64 + c * 8];
                    oacc[nt] = __builtin_amdgcn_mfma_f32_32x32x16_bf16(
                        pa, vf, oacc[nt], 0, 0, 0);
                }
            }
        }
    }

    // full row sum: the other 32 s of each tile live in the lane^32 partner
    l_part += __shfl_xor(l_part, 32);
    const float invl = 1.f / l_part;     // valid for q = qw0 + l32

    // epilogue: oacc rows are q=(r&3)+8*(r>>2)+4*hi, cols d=nt*32+l32
    bf16* op = O + (size_t)(b * T_ + qw0) * (H_ * HD_) + h * HD_;
    #pragma unroll
    for (int r = 0; r < 16; ++r) {
        const int qrow = (r & 3) + 8 * (r >> 2) + 4 * hi;
        const float il = __shfl(invl, qrow);
        #pragma unroll
        for (int nt = 0; nt < 4; ++nt)
            op[(size_t)qrow * (H_ * HD_) + nt * 32 + l32] =
                __float2bfloat16(oacc[nt][r] * il);
    }
}

extern "C" void kernel_launch(void* const* d_in, const int* in_sizes, int n_in,
                              void* d_out, int out_size, void* d_ws, size_t ws_size,
                              hipStream_t stream) {
    const float* x  = (const float*)d_in[0];
    const float* Wq = (const float*)d_in[1];
    const float* Wk = (const float*)d_in[2];
    const float* Wv = (const float*)d_in[3];
    const float* Wo = (const float*)d_in[4];
    float* out = (float*)d_out;

    const size_t NR = (size_t)B_ * T_;               // 4096
    bf16* ws = (bf16*)d_ws;
    bf16* xb    = ws;                                 // 4096*2048
    bf16* Wqkvt = xb + NR * D_;                       // 3072*2048
    bf16* Wot   = Wqkvt + (size_t)QKVSTR * D_;        // 2048*2048
    bf16* QKVb  = Wot + (size_t)D_ * D_;              // 4096*3072
    bf16* Vtg   = QKVb + NR * QKVSTR;                 // 2*4*128*2048
    bf16* Ab    = Vtg + (size_t)B_ * KV_ * HD_ * T_;  // 4096*2048

    const float qscale = 1.4426950408889634f / sqrtf((float)HD_);

    prep<<<6656, 256, 0, stream>>>(x, Wq, Wk, Wv, Wo, xb, Wqkvt, Wot, qscale);

    // fused QKV projection (256x256 tiles); V columns also written transposed
    gemm8<8, 4, bf16, 0, 1><<<dim3(QKVSTR / 256, NR / 256), 512, 0, stream>>>(
        xb, Wqkvt, QKVb, Vtg, (int)NR, QKVSTR, D_);

    flash9<<<dim3(H_, 32), 256, 0, stream>>>(QKVb, QKVb + 2048, Vtg, Ab);

    // output projection (128x256 tiles)
    gemm8<4, 2, float, 1, 0><<<dim3(D_ / 256, NR / 128), 512, 0, stream>>>(
        Ab, Wot, out, nullptr, (int)NR, D_, H_ * HD_);
}

// Round 6
// 274.378 us; speedup vs baseline: 1.0844x; 1.0474x over previous
//
#include <hip/hip_runtime.h>
#include <hip/hip_bf16.h>
#include <math.h>

#define B_ 2
#define T_ 2048
#define D_ 2048
#define H_ 16
#define KV_ 4
#define HD_ 128
#define REP_ 4
#define QKVSTR 3072

typedef __attribute__((ext_vector_type(8))) short s16x8;
typedef __attribute__((ext_vector_type(4))) short s16x4;
typedef __attribute__((ext_vector_type(4))) float f32x4;
typedef __attribute__((ext_vector_type(16))) float f32x16;
typedef __hip_bfloat16 bf16;

__device__ __forceinline__ short f2bf(float x) {
    bf16 h = __float2bfloat16(x);
    return *reinterpret_cast<short*>(&h);
}

__device__ __forceinline__ void gl2lds16(const void* g, void* l) {
    __builtin_amdgcn_global_load_lds(
        (const __attribute__((address_space(1))) char*)g,
        (__attribute__((address_space(3))) char*)l, 16, 0, 0);
}

// ---------------- fused prep: cast x -> bf16  +  all 4 weight transposes ----
// v2: the old 64x72-short tile had row stride 36 words, gcd(36,32)=4 -> the
// (t&3)*16 column groups all aliased (16*36 = 0 mod 32): BOTH the scalar-b16
// write phase and the strided read phase were 8-way bank-conflicted, and the
// kernel ran ~60-70 us for ~110 MB (accounting across rounds 0/2 forces
// prep >= 51 us). New scheme per 64x64 tile:
//   write: thread owns k-pair r2 = t>>3 (rows k0+2r2, k0+2r2+1) x 8 cols
//          (c0 = (t&7)*8). One v_cvt_pk_bf16_f32 per column packs
//          {lo = even k, hi = odd k} = exactly the transposed output u32.
//          8x ds_write_b32 into u32 tileT with 33-word row stride:
//          bank = (33(c0+j)+r2)%32 = (c0+j+r2)%32 -> 2-way (free).
//   read:  thread (n = t>>2, q = t&3) reads 8 consecutive u32 of transposed
//          row n: bank = (n+8q+j)%32 -> 2-way (free). Two 16B global stores.
// 16 conflict-free b32 LDS ops/thread vs 32 8-way-conflicted b16 ops.
__global__ __launch_bounds__(256) void prep(const float* __restrict__ x,
                                            const float* __restrict__ Wq,
                                            const float* __restrict__ Wk,
                                            const float* __restrict__ Wv,
                                            const float* __restrict__ Wo,
                                            bf16* __restrict__ xb,
                                            bf16* __restrict__ Wqkvt,
                                            bf16* __restrict__ Wot,
                                            float qscale) {
    const int bid = blockIdx.x;
    const int t = threadIdx.x;
    if (bid < 4096) {
        int i = (bid * 256 + t) * 8;
        float4 a = *(const float4*)(x + i);
        float4 b = *(const float4*)(x + i + 4);
        short o[8] = {f2bf(a.x), f2bf(a.y), f2bf(a.z), f2bf(a.w),
                      f2bf(b.x), f2bf(b.y), f2bf(b.z), f2bf(b.w)};
        *(s16x8*)(xb + i) = *(const s16x8*)o;
        return;
    }
    __shared__ unsigned tileT[64 * 33];   // 8448 B, u32 = one k-pair
    const float* W; bf16* dst; int N; float scale; int seg;
    if (bid < 5120)      { seg = bid - 4096; W = Wq; dst = Wqkvt;                      N = 2048; scale = qscale; }
    else if (bid < 5376) { seg = bid - 5120; W = Wk; dst = Wqkvt + (size_t)2048 * D_;  N = 512;  scale = 1.f; }
    else if (bid < 5632) { seg = bid - 5376; W = Wv; dst = Wqkvt + (size_t)2560 * D_;  N = 512;  scale = 1.f; }
    else                 { seg = bid - 5632; W = Wo; dst = Wot;                        N = 2048; scale = 1.f; }
    const int k0 = (seg & 31) * 64, n0 = (seg >> 5) * 64;

    const int r2 = t >> 3;            // k-pair 0..31
    const int c0 = (t & 7) * 8;       // col offset 0..56
    const float* srcA = W + (size_t)(k0 + 2 * r2) * N + n0 + c0;
    const float* srcB = srcA + N;
    float4 a0 = *(const float4*)(srcA);
    float4 a1 = *(const float4*)(srcA + 4);
    float4 b0 = *(const float4*)(srcB);
    float4 b1 = *(const float4*)(srcB + 4);
    float ra[8] = {a0.x, a0.y, a0.z, a0.w, a1.x, a1.y, a1.z, a1.w};
    float rb[8] = {b0.x, b0.y, b0.z, b0.w, b1.x, b1.y, b1.z, b1.w};
    #pragma unroll
    for (int j = 0; j < 8; ++j) {
        unsigned p;
        asm("v_cvt_pk_bf16_f32 %0, %1, %2"
            : "=v"(p) : "v"(ra[j] * scale), "v"(rb[j] * scale));
        tileT[(c0 + j) * 33 + r2] = p;
    }
    __syncthreads();
    const int n = t >> 2, q = t & 3;
    union { unsigned u[8]; s16x8 v[2]; } ou;
    #pragma unroll
    for (int j = 0; j < 8; ++j) ou.u[j] = tileT[n * 33 + q * 8 + j];
    bf16* d = dst + (size_t)(n0 + n) * D_ + k0 + q * 16;
    *(s16x8*)(d)     = ou.v[0];
    *(s16x8*)(d + 8) = ou.v[1];
}

// ---- bf16 NT GEMM, 8-wave BMxBN tile, counted-vmcnt pipeline (T4) ---------
// BM = MI*32 rows x BN = NJ*64 cols per block, 8 waves (512 thr, wave grid
// 2Mx4N, per-wave MI*16 x NJ*16 out), BK=64, double-buffered LDS.
// Pipeline per K-step t (the m218 lever: vmcnt NEVER drains to 0 mid-loop):
//   issue next tile's (MI/2+NJ) global_load_lds -> buf[(t+1)&1]
//   s_waitcnt vmcnt(MI/2+NJ)  (waits only L(t); L(t+1) stays in flight)
//   s_barrier           (A: everyone's L(t) landed; prior readers of
//                        buf[(t+1)&1] finished at iter t-1's barrier B)
//   ds_read_b128 frags + MFMA per wave from buf[t&1]
//   s_waitcnt lgkmcnt(0); s_barrier   (B: my reads of buf[t&1] complete
//                        before any wave's L(t+2) can overwrite it)
// Raw s_barrier (not __syncthreads) avoids the compiler's vmcnt(0) drain.
// gemm1: MI=8,NJ=3 -> 256x192, grid 16x16 = 256 blocks = EXACT 1/CU
//        coverage (the round-4 256x256 config had 192 blocks -> 25% of CUs
//        idle, 76 us), 112 KiB LDS.
// gemm2: MI=4,NJ=4 -> 128x256, 256 blocks,  96 KiB LDS, 1/CU.
template<int MI, int NJ, typename OUTT, int ROUND, int WVT>
__global__ __launch_bounds__(512, 2) void gemm8(const bf16* __restrict__ A,
                                                const bf16* __restrict__ Bt,
                                                OUTT* __restrict__ C,
                                                bf16* __restrict__ Vtg,
                                                int M, int N, int K) {
    constexpr int ASZ = MI * 2048;          // shorts per A buffer (MI*32 x 64)
    constexpr int BSZ = NJ * 4096;          // shorts per B buffer (NJ*64 x 64)
    __shared__ short smem[2 * (ASZ + BSZ)];
    const int tid = threadIdx.x;
    const int lane = tid & 63;
    const int wave = tid >> 6;
    const int quad = lane >> 4;
    const int l16 = lane & 15;
    const int wr = wave >> 2, wc = wave & 3;      // 2 x 4 wave grid
    const int row0 = blockIdx.y * (MI * 32);
    const int col0 = blockIdx.x * (NJ * 64);
    const int NT = K >> 6;

    f32x4 acc[MI][NJ] = {};

    const bf16* Ap = A + (size_t)row0 * K;
    const bf16* Bp = Bt + (size_t)col0 * K;

    auto stage = [&](int t) {
        const int bo = (t & 1) * (ASZ + BSZ);
        const int k0 = t * 64;
        #pragma unroll
        for (int i = 0; i < MI / 2; ++i) {
            int g = i * 512 + tid;
            int row = g >> 3;
            int cs = (g & 7) ^ (row & 7);
            gl2lds16(Ap + (size_t)row * K + k0 + cs * 8, &smem[bo + g * 8]);
        }
        #pragma unroll
        for (int i = 0; i < NJ; ++i) {
            int g = i * 512 + tid;
            int row = g >> 3;
            int cs = (g & 7) ^ (row & 7);
            gl2lds16(Bp + (size_t)row * K + k0 + cs * 8, &smem[bo + ASZ + g * 8]);
        }
    };

    constexpr int VM = MI / 2 + NJ;         // loads per stage = in-flight count
    static_assert(VM == 6 || VM == 7, "add a vmcnt literal for this shape");

    stage(0);
    for (int t = 0; t < NT; ++t) {
        if (t + 1 < NT) {
            stage(t + 1);
            // wait L(t) only; the VM loads of L(t+1) stay in flight
            if constexpr (VM == 7) asm volatile("s_waitcnt vmcnt(7)" ::: "memory");
            else                   asm volatile("s_waitcnt vmcnt(6)" ::: "memory");
        } else {
            asm volatile("s_waitcnt vmcnt(0)" ::: "memory");
        }
        __builtin_amdgcn_s_barrier();
        asm volatile("" ::: "memory");            // no LDS reads hoist above A

        const int bo = (t & 1) * (ASZ + BSZ);
        #pragma unroll
        for (int kk = 0; kk < 2; ++kk) {
            s16x8 af[MI], bfr[NJ];
            #pragma unroll
            for (int i = 0; i < MI; ++i) {
                int row = wr * (MI * 16) + i * 16 + l16;
                int c = (kk * 4 + quad) ^ (row & 7);
                af[i] = *(const s16x8*)&smem[bo + row * 64 + c * 8];
            }
            #pragma unroll
            for (int j = 0; j < NJ; ++j) {
                int row = wc * (NJ * 16) + j * 16 + l16;
                int c = (kk * 4 + quad) ^ (row & 7);
                bfr[j] = *(const s16x8*)&smem[bo + ASZ + row * 64 + c * 8];
            }
            __builtin_amdgcn_s_setprio(1);
            #pragma unroll
            for (int i = 0; i < MI; ++i)
                #pragma unroll
                for (int j = 0; j < NJ; ++j)
                    acc[i][j] = __builtin_amdgcn_mfma_f32_16x16x32_bf16(
                        af[i], bfr[j], acc[i][j], 0, 0, 0);
            __builtin_amdgcn_s_setprio(0);
        }
        // my ds_reads of buf[t&1] complete before crossing B
        asm volatile("s_waitcnt lgkmcnt(0)" ::: "memory");
        __builtin_amdgcn_s_barrier();
        asm volatile("" ::: "memory");
    }

    #pragma unroll
    for (int i = 0; i < MI; ++i) {
        #pragma unroll
        for (int j = 0; j < NJ; ++j) {
            const int col = col0 + wc * (NJ * 16) + j * 16 + l16;
            const int rowb = row0 + wr * (MI * 16) + i * 16 + quad * 4;
            #pragma unroll
            for (int r = 0; r < 4; ++r) {
                float v = acc[i][j][r];
                if (ROUND) v = rintf(v * 1e4f) * 1e-4f;
                if constexpr (sizeof(OUTT) == 2)
                    C[(size_t)(rowb + r) * N + col] = __float2bfloat16(v);
                else
                    C[(size_t)(rowb + r) * N + col] = v;
            }
            if constexpr (WVT) {
                if (col >= 2560) {
                    const int dcol = (col - 2560) & 127;
                    const int g = (col - 2560) >> 7;
                    const int b = rowb >> 11;
                    const int t = rowb & 2047;
                    short pk[4] = {f2bf(acc[i][j][0]), f2bf(acc[i][j][1]),
                                   f2bf(acc[i][j][2]), f2bf(acc[i][j][3])};
                    *(s16x4*)&Vtg[(size_t)((b * KV_ + g) * HD_ + dcol) * T_ + t] =
                        *(const s16x4*)pk;
                }
            }
        }
    }
}

// ---------------- MFMA flash attention v9 (best measured: 75 us) -----------
// 32x32x16, swapped QK^T, P in registers via cvt_pk+permlane32_swap, LDS
// double-buffer 2x32 KiB, one __syncthreads per iter (its vmcnt(0) drain IS
// the intended depth-1 pipeline semantics). Grid is 512 blocks = 2/CU hard
// cap (32 q/wave fixes total waves at 8/CU); flash10 proved removing the
// intra-block dbuf at this residency costs +28 us. Kept verbatim.
__global__ __launch_bounds__(256, 2) void flash9(const bf16* __restrict__ Q,
                                                 const bf16* __restrict__ K,
                                                 const bf16* __restrict__ Vtg,
                                                 bf16* __restrict__ O) {
    __shared__ short smem[32768];   // 2 buffers x (Kt [64s][128d] + Vt [128d][64s])

    const int h = blockIdx.x;
    const int b = blockIdx.y & 1;
    const int qt = 15 - (blockIdx.y >> 1);   // heavy blocks first (LPT)
    const int g = h >> 2;
    const int tid = threadIdx.x;
    const int lane = tid & 63;
    const int wave = tid >> 6;
    const int l32 = lane & 31;
    const int hi = lane >> 5;                // which k-half of the frag
    const int qw0 = qt * 128 + wave * 32;    // this wave's first q row
    const int qg = qw0 + l32;                // this lane's q row

    // Q fragments (B-operand): n=l32 (q), k = hi*8 + j (d); 8 k-tiles of 16
    s16x8 qf[8];
    {
        const bf16* qp = Q + (size_t)(b * T_ + qg) * QKVSTR + h * HD_ + hi * 8;
        #pragma unroll
        for (int kt = 0; kt < 8; ++kt) qf[kt] = *(const s16x8*)(qp + kt * 16);
    }

    const bf16* Kp = K + (size_t)(b * T_) * QKVSTR + g * HD_;
    const bf16* Vp = Vtg + (size_t)((b * KV_ + g) * HD_) * T_;

    float l_part = 0.f;
    f32x16 oacc[4] = {};

    const int jmax = 2 * qt + 1;

    // prologue: stage tile 0 into buffer 0
    #pragma unroll
    for (int i = 0; i < 4; ++i) {
        int g2 = i * 256 + tid;
        int s = g2 >> 4;
        int cs = (g2 & 15) ^ (s & 15);
        gl2lds16(Kp + (size_t)s * QKVSTR + cs * 8, &smem[g2 * 8]);
    }
    #pragma unroll
    for (int i = 0; i < 4; ++i) {
        int g2 = i * 256 + tid;
        int d = g2 >> 3;
        int cs = (g2 & 7) ^ (d & 7);
        gl2lds16(Vp + (size_t)d * T_ + cs * 8, &smem[8192 + g2 * 8]);
    }

    for (int j = 0; j <= jmax; ++j) {
        const int kb = (j & 1) << 14;        // 16384 shorts per buffer
        // drains tile j's loads (vmcnt(0) before s_barrier) AND ensures all
        // waves finished reading the buffer tile j+1 is about to overwrite
        __syncthreads();

        if (j < jmax) {                      // stage tile j+1 (block-uniform)
            const int s0n = (j + 1) * 64;
            const int nb = ((j + 1) & 1) << 14;
            #pragma unroll
            for (int i = 0; i < 4; ++i) {
                int g2 = i * 256 + tid;
                int s = g2 >> 4;
                int cs = (g2 & 15) ^ (s & 15);
                gl2lds16(Kp + (size_t)(s0n + s) * QKVSTR + cs * 8, &smem[nb + g2 * 8]);
            }
            #pragma unroll
            for (int i = 0; i < 4; ++i) {
                int g2 = i * 256 + tid;
                int d = g2 >> 3;
                int cs = (g2 & 7) ^ (d & 7);
                gl2lds16(Vp + (size_t)d * T_ + s0n + cs * 8, &smem[nb + 8192 + g2 * 8]);
            }
        }

        const int s0 = j * 64;
        if (s0 >= qw0 + 32) continue;        // tile fully masked for this wave

        // S = K·Q^T : sacc[mt] has n=q=l32, m=s (two 32-s halves)
        f32x16 sacc[2] = {};
        #pragma unroll
        for (int kt = 0; kt < 8; ++kt) {
            #pragma unroll
            for (int mt = 0; mt < 2; ++mt) {
                int s = mt * 32 + l32;
                int c = (kt * 2 + hi) ^ (s & 15);
                const s16x8 kf = *(const s16x8*)&smem[kb + s * 128 + c * 8];
                sacc[mt] = __builtin_amdgcn_mfma_f32_32x32x16_bf16(
                    kf, qf[kt], sacc[mt], 0, 0, 0);
            }
        }

        const bool diagw = (s0 + 63 > qw0);
        #pragma unroll
        for (int mt = 0; mt < 2; ++mt) {
            // static softmax: P = exp2(s) (scale folded into Wq); masked -> 0
            #pragma unroll
            for (int r = 0; r < 16; ++r) {
                float sv = sacc[mt][r];
                if (diagw) {
                    int sg = s0 + mt * 32 + (r & 3) + 8 * (r >> 2) + 4 * hi;
                    if (sg > qg) sv = -INFINITY;
                }
                float e = exp2f(sv);
                sacc[mt][r] = e;
                l_part += e;
            }
            // P -> bf16 A-frags in registers: regs o..o+7 cover the 16-s
            // k-tile kts; cvt_pk pairs + permlane32_swap fix the lane-half
            // split: swap(w01,w45) -> {A0,A2}, swap(w23,w67) -> {A1,A3}.
            #pragma unroll
            for (int kts = 0; kts < 2; ++kts) {
                const int o = kts * 8;
                unsigned w01, w23, w45, w67;
                asm("v_cvt_pk_bf16_f32 %0, %1, %2"
                    : "=v"(w01) : "v"(sacc[mt][o + 0]), "v"(sacc[mt][o + 1]));
                asm("v_cvt_pk_bf16_f32 %0, %1, %2"
                    : "=v"(w23) : "v"(sacc[mt][o + 2]), "v"(sacc[mt][o + 3]));
                asm("v_cvt_pk_bf16_f32 %0, %1, %2"
                    : "=v"(w45) : "v"(sacc[mt][o + 4]), "v"(sacc[mt][o + 5]));
                asm("v_cvt_pk_bf16_f32 %0, %1, %2"
                    : "=v"(w67) : "v"(sacc[mt][o + 6]), "v"(sacc[mt][o + 7]));
                asm("v_permlane32_swap_b32 %0, %1" : "+v"(w01), "+v"(w45));
                asm("v_permlane32_swap_b32 %0, %1" : "+v"(w23), "+v"(w67));
                union { unsigned u[4]; s16x8 v; } pu;
                pu.u[0] = w01; pu.u[1] = w23; pu.u[2] = w45; pu.u[3] = w67;
                const s16x8 pa = pu.v;
                // O += P·V : A=pa (m=q=l32, k=s), B=V (k=s, n=d=l32)
                #pragma unroll
                for (int nt = 0; nt < 4; ++nt) {
                    int d = nt * 32 + l32;
                    int c = ((mt * 2 + kts) * 2 + hi) ^ (d & 7);
                    const s16x8 vf = *(const s16x8*)&smem[kb + 8192 + d * 64 + c * 8];
                    oacc[nt] = __builtin_amdgcn_mfma_f32_32x32x16_bf16(
                        pa, vf, oacc[nt], 0, 0, 0);
                }
            }
        }
    }

    // full row sum: the other 32 s of each tile live in the lane^32 partner
    l_part += __shfl_xor(l_part, 32);
    const float invl = 1.f / l_part;     // valid for q = qw0 + l32

    // epilogue: oacc rows are q=(r&3)+8*(r>>2)+4*hi, cols d=nt*32+l32
    bf16* op = O + (size_t)(b * T_ + qw0) * (H_ * HD_) + h * HD_;
    #pragma unroll
    for (int r = 0; r < 16; ++r) {
        const int qrow = (r & 3) + 8 * (r >> 2) + 4 * hi;
        const float il = __shfl(invl, qrow);
        #pragma unroll
        for (int nt = 0; nt < 4; ++nt)
            op[(size_t)qrow * (H_ * HD_) + nt * 32 + l32] =
                __float2bfloat16(oacc[nt][r] * il);
    }
}

extern "C" void kernel_launch(void* const* d_in, const int* in_sizes, int n_in,
                              void* d_out, int out_size, void* d_ws, size_t ws_size,
                              hipStream_t stream) {
    const float* x  = (const float*)d_in[0];
    const float* Wq = (const float*)d_in[1];
    const float* Wk = (const float*)d_in[2];
    const float* Wv = (const float*)d_in[3];
    const float* Wo = (const float*)d_in[4];
    float* out = (float*)d_out;

    const size_t NR = (size_t)B_ * T_;               // 4096
    bf16* ws = (bf16*)d_ws;
    bf16* xb    = ws;                                 // 4096*2048
    bf16* Wqkvt = xb + NR * D_;                       // 3072*2048
    bf16* Wot   = Wqkvt + (size_t)QKVSTR * D_;        // 2048*2048
    bf16* QKVb  = Wot + (size_t)D_ * D_;              // 4096*3072
    bf16* Vtg   = QKVb + NR * QKVSTR;                 // 2*4*128*2048
    bf16* Ab    = Vtg + (size_t)B_ * KV_ * HD_ * T_;  // 4096*2048

    const float qscale = 1.4426950408889634f / sqrtf((float)HD_);

    prep<<<6656, 256, 0, stream>>>(x, Wq, Wk, Wv, Wo, xb, Wqkvt, Wot, qscale);

    // fused QKV projection (256x192 tiles, 256 blocks = exact CU coverage);
    // V columns also written transposed into Vtg
    gemm8<8, 3, bf16, 0, 1><<<dim3(QKVSTR / 192, NR / 256), 512, 0, stream>>>(
        xb, Wqkvt, QKVb, Vtg, (int)NR, QKVSTR, D_);

    flash9<<<dim3(H_, 32), 256, 0, stream>>>(QKVb, QKVb + 2048, Vtg, Ab);

    // output projection (128x256 tiles, 256 blocks)
    gemm8<4, 4, float, 1, 0><<<dim3(D_ / 256, NR / 128), 512, 0, stream>>>(
        Ab, Wot, out, nullptr, (int)NR, D_, H_ * HD_);
}